// Round 1
// baseline (613.451 us; speedup 1.0000x reference)
//
#include <hip/hip_runtime.h>
#include <math.h>

#define B_ 128
#define N_ 2048
#define D_ 256
#define NHEADS 32   // 2 head-sets * 16 heads
#define CHUNK 128   // nodes per k_attn block (x chunk fully LDS-resident)
#define NCH 16      // N_/CHUNK chunks per graph

// ws layout (float offsets)
#define POOLEDP_OFF 0               // 16*B*256 = 524288 (per-chunk max partials)
#define PHI_OFF     524288          // B*32*256 ushort = 524288 fl
#define PLO_OFF     1048576         // 524288 fl
#define ML_OFF      1572864         // B*32*NCH*2 = 131072
#define FEATP_OFF   1703936         // NCH*B*256*32 = 16777216 (d-major)
                                    // end = 18481152 fl = 74 MB

// k_attn dynamic-LDS byte offsets (141824 B total, 1 block/CU)
#define XHI_S  0        // [128 n][256 d] bf16, row stride 512 B, 16B-slot XOR swizzle
#define XLO_S  65536    // same layout
#define ATT_S  131072   // [32 h][136 n] bf16, row stride 272 B = 8704 B
#define SMAX_S 139776   // [8 w][32 h] f32
#define SSUM_S 140800   // [8 w][32 h] f32
#define LDS_BYTES 141824

typedef __attribute__((ext_vector_type(8))) short short8;
typedef __attribute__((ext_vector_type(4))) float f32x4;

__device__ __forceinline__ unsigned short f2bf(float f) {   // RNE
    unsigned u = __float_as_uint(f);
    u += 0x7fff + ((u >> 16) & 1);
    return (unsigned short)(u >> 16);
}
__device__ __forceinline__ float bf2f(unsigned short h) {
    return __uint_as_float(((unsigned)h) << 16);
}
__device__ __forceinline__ unsigned pack2bf(float a, float b) {
    return (unsigned)f2bf(a) | ((unsigned)f2bf(b) << 16);
}
// 16B-slot swizzle within a 512 B row: spreads consecutive rows (phase-1 b128
// reads, 2-way) AND stride-8 rows (phase-3 u16 gathers, 4 distinct slots).
__device__ __forceinline__ unsigned xsw(int row) {
    return (unsigned)((row ^ (row >> 3)) & 7) << 4;
}

// pure max-pool, per-chunk partials (no atomics, no init kernel). grid B*16.
__global__ __launch_bounds__(256) void k_pool(const float* __restrict__ inp,
                                              float* __restrict__ pooledp) {
    int b = blockIdx.x >> 4;
    int ch = blockIdx.x & 15;
    int t = threadIdx.x;
    int sub = t >> 6;            // row phase 0..3
    int dq = (t & 63) * 4;       // column quad
    const float* p = inp + ((size_t)(b * N_ + ch * 128 + sub)) * D_ + dq;
    float4 m = {-INFINITY, -INFINITY, -INFINITY, -INFINITY};
#pragma unroll 4
    for (int i = 0; i < 32; ++i) {
        float4 v = *(const float4*)(p + (size_t)i * 4 * D_);
        m.x = fmaxf(m.x, v.x); m.y = fmaxf(m.y, v.y);
        m.z = fmaxf(m.z, v.z); m.w = fmaxf(m.w, v.w);
    }
    __shared__ float sm[4 * 256];
    sm[sub * 256 + dq + 0] = m.x;
    sm[sub * 256 + dq + 1] = m.y;
    sm[sub * 256 + dq + 2] = m.z;
    sm[sub * 256 + dq + 3] = m.w;
    __syncthreads();
    float v = fmaxf(fmaxf(sm[t], sm[256 + t]), fmaxf(sm[512 + t], sm[768 + t]));
    pooledp[((size_t)ch * B_ + b) * 256 + t] = v;
}

// merge pool partials, q = pooled @ Wq^T (both sets), P = q @ Wk -> bf16 hi/lo
__global__ __launch_bounds__(256) void k_qp(const float* __restrict__ pooledp,
                                            const float* __restrict__ Wq0,
                                            const float* __restrict__ Wq1,
                                            const float* __restrict__ Wk,
                                            unsigned short* __restrict__ Phi,
                                            unsigned short* __restrict__ Plo) {
    __shared__ float pl[D_];
    __shared__ float ql[1024];
    int b = blockIdx.x, t = threadIdx.x;
    float pv = -INFINITY;
#pragma unroll
    for (int i = 0; i < 16; ++i)
        pv = fmaxf(pv, pooledp[((size_t)i * B_ + b) * 256 + t]);
    pl[t] = pv;
    __syncthreads();
    for (int rep = 0; rep < 4; ++rep) {
        int idx = rep * 256 + t;                 // 0..1023
        const float* Wq = (idx < 512) ? Wq0 : Wq1;
        int row = idx & 511;
        const float4* wr = (const float4*)(Wq + (size_t)row * D_);
        float acc = 0.0f;
        for (int dqi = 0; dqi < 64; ++dqi) {
            float4 w = wr[dqi];
            const float* pp = &pl[dqi * 4];
            acc += w.x * pp[0] + w.y * pp[1] + w.z * pp[2] + w.w * pp[3];
        }
        ql[idx] = acc;
    }
    __syncthreads();
    float wk[32];
#pragma unroll
    for (int k = 0; k < 32; ++k) wk[k] = Wk[k * D_ + t];
    for (int j = 0; j < NHEADS; ++j) {
        const float* q = &ql[(j >> 4) * 512 + (j & 15) * 32];
        float acc = 0.0f;
#pragma unroll
        for (int k = 0; k < 32; ++k) acc = fmaf(q[k], wk[k], acc);
        unsigned short hi = f2bf(acc);
        unsigned short lo = f2bf(acc - bf2f(hi));
        Phi[((size_t)b * NHEADS + j) * D_ + t] = hi;
        Plo[((size_t)b * NHEADS + j) * D_ + t] = lo;
    }
}

// Fused attention, flash-style chunk residency: per block 128 nodes, x staged
// ONCE from inp fp32 -> LDS bf16 hi/lo (swizzled). Phase 1 S^T MFMA (hi/lo),
// phase 2 chunk softmax, phase 3 O = att*x with in-LDS u16 transpose gather.
// grid = B*16 (b, ns); block 512 = 8 waves; dyn LDS 142 KB -> 1 block/CU.
__global__ __launch_bounds__(512, 2) void k_attn(const float* __restrict__ inp,
                                                 const unsigned short* __restrict__ Phi,
                                                 const unsigned short* __restrict__ Plo,
                                                 float* __restrict__ ml,
                                                 float* __restrict__ featp) {
    extern __shared__ unsigned char smem[];
    float* smax = (float*)(smem + SMAX_S);        // [8][32]
    float* ssum = (float*)(smem + SSUM_S);        // [8][32]

    int b = blockIdx.x >> 4, ns = blockIdx.x & 15;
    int t = threadIdx.x;
    int w = t >> 6;                // wave id 0..7
    int lane = t & 63;
    int lq = lane >> 4;            // quad 0..3
    int lm = lane & 15;
    size_t gnode0 = (size_t)b * N_ + (size_t)ns * CHUNK;

    // ---------------- stage: inp fp32 -> LDS bf16 hi/lo ----------------
    // per iter: each wave writes one full row (64 lanes x 4 floats).
#pragma unroll
    for (int i = 0; i < 16; ++i) {
        int row = i * 8 + w;
        float4 v = *(const float4*)(inp + (gnode0 + row) * D_ + lane * 4);
        ushort4 h4, l4;
        h4.x = f2bf(v.x); l4.x = f2bf(v.x - bf2f(h4.x));
        h4.y = f2bf(v.y); l4.y = f2bf(v.y - bf2f(h4.y));
        h4.z = f2bf(v.z); l4.z = f2bf(v.z - bf2f(h4.z));
        h4.w = f2bf(v.w); l4.w = f2bf(v.w - bf2f(h4.w));
        unsigned byteoff = (unsigned)row * 512u + (((unsigned)lane * 8u) ^ xsw(row));
        *(ushort4*)(smem + XHI_S + byteoff) = h4;
        *(ushort4*)(smem + XLO_S + byteoff) = l4;
    }
    __syncthreads();

    // ---------------- phase 1: S^T accumulate (no barriers) ----------------
    f32x4 acc_s[2];
    acc_s[0] = (f32x4){0.f, 0.f, 0.f, 0.f};
    acc_s[1] = (f32x4){0.f, 0.f, 0.f, 0.f};
    int arow = w * 16 + lm;                       // A-frag row -> node
    unsigned abase = (unsigned)arow * 512u;
    unsigned asl = xsw(arow);
#pragma unroll
    for (int dc = 0; dc < 8; ++dc) {
        short8 bh[2], bl[2];
#pragma unroll
        for (int ht = 0; ht < 2; ++ht) {
            size_t poff = ((size_t)b * NHEADS + ht * 16 + lm) * D_ + dc * 32 + lq * 8;
            bh[ht] = *(const short8*)(Phi + poff);
            bl[ht] = *(const short8*)(Plo + poff);
        }
        unsigned doff = (((unsigned)(dc * 32 + lq * 8)) * 2u) ^ asl;
        short8 ah = *(const short8*)(smem + XHI_S + abase + doff);
        short8 al = *(const short8*)(smem + XLO_S + abase + doff);
#pragma unroll
        for (int ht = 0; ht < 2; ++ht) {
            acc_s[ht] = __builtin_amdgcn_mfma_f32_16x16x32_bf16(ah, bh[ht], acc_s[ht], 0, 0, 0);
            acc_s[ht] = __builtin_amdgcn_mfma_f32_16x16x32_bf16(ah, bl[ht], acc_s[ht], 0, 0, 0);
            acc_s[ht] = __builtin_amdgcn_mfma_f32_16x16x32_bf16(al, bh[ht], acc_s[ht], 0, 0, 0);
        }
    }

    // ---------------- phase 2: chunk softmax ----------------
    // lane holds S^T[n = w*16 + lq*4 + r][h = ht*16 + lm]
    float bm[2];
#pragma unroll
    for (int ht = 0; ht < 2; ++ht) {
        float m = fmaxf(fmaxf(acc_s[ht][0], acc_s[ht][1]),
                        fmaxf(acc_s[ht][2], acc_s[ht][3]));
        m = fmaxf(m, __shfl_xor(m, 16));
        m = fmaxf(m, __shfl_xor(m, 32));
        if (lane < 16) smax[w * 32 + ht * 16 + lane] = m;
    }
    __syncthreads();
#pragma unroll
    for (int ht = 0; ht < 2; ++ht) {
        float mm = smax[ht * 16 + lm];
#pragma unroll
        for (int w2 = 1; w2 < 8; ++w2) mm = fmaxf(mm, smax[w2 * 32 + ht * 16 + lm]);
        bm[ht] = mm;
    }
#pragma unroll
    for (int ht = 0; ht < 2; ++ht) {
        float e0 = __expf(acc_s[ht][0] - bm[ht]);
        float e1 = __expf(acc_s[ht][1] - bm[ht]);
        float e2 = __expf(acc_s[ht][2] - bm[ht]);
        float e3 = __expf(acc_s[ht][3] - bm[ht]);
        float s = (e0 + e1) + (e2 + e3);
        uint2 pk;
        pk.x = pack2bf(e0, e1);
        pk.y = pack2bf(e2, e3);
        *(uint2*)(smem + ATT_S + (size_t)(ht * 16 + lm) * 272 + w * 32 + lq * 8) = pk;
        s += __shfl_xor(s, 16);
        s += __shfl_xor(s, 32);
        if (lane < 16) ssum[w * 32 + ht * 16 + lane] = s;
    }
    __syncthreads();
    if (t < 32) {
        float mB = smax[t];
        float l = ssum[t];
#pragma unroll
        for (int w2 = 1; w2 < 8; ++w2) {
            mB = fmaxf(mB, smax[w2 * 32 + t]);
            l += ssum[w2 * 32 + t];
        }
        float* mlp = ml + ((size_t)(b * NHEADS + t) * NCH + ns) * 2;
        mlp[0] = mB;
        mlp[1] = l;
    }

    // ---------------- phase 3: O = att * x (in-LDS transpose gather) -------
    f32x4 acc_o[2][2];
#pragma unroll
    for (int ht = 0; ht < 2; ++ht)
#pragma unroll
        for (int dt = 0; dt < 2; ++dt) acc_o[ht][dt] = (f32x4){0.f, 0.f, 0.f, 0.f};

    int d0w = w * 32;              // each wave owns 32 d-columns
#pragma unroll
    for (int c = 0; c < 4; ++c) {  // K-chunks of 32 nodes
        short8 a0 = *(const short8*)(smem + ATT_S + (size_t)lm * 272 + c * 64 + lq * 16);
        short8 a1 = *(const short8*)(smem + ATT_S + (size_t)(16 + lm) * 272 + c * 64 + lq * 16);
#pragma unroll
        for (int dt = 0; dt < 2; ++dt) {
            unsigned d2 = (unsigned)(d0w + dt * 16 + lm) * 2u;
            int n0 = c * 32 + lq * 8;
            short8 bf;
#pragma unroll
            for (int j = 0; j < 8; ++j) {
                int n = n0 + j;
                unsigned byteoff = (unsigned)n * 512u + (d2 ^ xsw(n));
                bf[j] = *(const short*)(smem + XHI_S + byteoff);
            }
            acc_o[0][dt] = __builtin_amdgcn_mfma_f32_16x16x32_bf16(a0, bf, acc_o[0][dt], 0, 0, 0);
            acc_o[1][dt] = __builtin_amdgcn_mfma_f32_16x16x32_bf16(a1, bf, acc_o[1][dt], 0, 0, 0);
        }
    }
    // write featp (d-major: [ns][b][d][h]); C/D: col=lane&15 (d), row=lq*4+r (h)
    float* fb = featp + ((size_t)(ns * B_ + b)) * D_ * NHEADS;
#pragma unroll
    for (int ht = 0; ht < 2; ++ht)
#pragma unroll
        for (int dt = 0; dt < 2; ++dt) {
            int d = d0w + dt * 16 + lm;
            int h0 = ht * 16 + lq * 4;
            *(f32x4*)(fb + (size_t)d * NHEADS + h0) = acc_o[ht][dt];
        }
}

// epilogue: merge 16 chunk partials, feat@We^T, dx, dx@Wout^T + bias, leaky
__global__ __launch_bounds__(256) void k_out(const float* __restrict__ featp,
                                             const float* __restrict__ ml,
                                             const float* __restrict__ We,
                                             const float* __restrict__ Wout,
                                             const float* __restrict__ bout,
                                             float* __restrict__ out) {
    __shared__ float f[NHEADS * 257];
    __shared__ float bhrs[512];
    __shared__ float dxs[256];
    __shared__ float wns[NCH * 32];
    __shared__ float linv2[32];
    int b = blockIdx.x, t = threadIdx.x;
    if (t < 32) {
        const float* mlb = ml + ((size_t)b * NHEADS + t) * (NCH * 2);
        float M = mlb[0];
#pragma unroll
        for (int i = 1; i < NCH; ++i) M = fmaxf(M, mlb[2 * i]);
        float L = 0.0f;
#pragma unroll
        for (int i = 0; i < NCH; ++i) {
            float e = __expf(mlb[2 * i] - M);
            wns[i * 32 + t] = e;
            L += e * mlb[2 * i + 1];
        }
        linv2[t] = 1.0f / L;
    }
    __syncthreads();
    float fj[32];
#pragma unroll
    for (int j = 0; j < 32; ++j) fj[j] = 0.0f;
    for (int ns = 0; ns < NCH; ++ns) {
        const float* fp = featp + ((size_t)(ns * B_ + b) * D_ + t) * NHEADS;
#pragma unroll
        for (int j4 = 0; j4 < 8; ++j4) {
            float4 v = *(const float4*)(fp + j4 * 4);
            fj[j4 * 4 + 0] += wns[ns * 32 + j4 * 4 + 0] * v.x;
            fj[j4 * 4 + 1] += wns[ns * 32 + j4 * 4 + 1] * v.y;
            fj[j4 * 4 + 2] += wns[ns * 32 + j4 * 4 + 2] * v.z;
            fj[j4 * 4 + 3] += wns[ns * 32 + j4 * 4 + 3] * v.w;
        }
    }
#pragma unroll
    for (int j = 0; j < 32; ++j) f[j * 257 + t] = fj[j] * linv2[j];
    __syncthreads();
    for (int rep = 0; rep < 2; ++rep) {
        int idx = rep * 256 + t;
        int j = idx >> 4, r = idx & 15;
        const float* wrow = We + (size_t)r * D_;
        const float* ff = &f[j * 257];
        float acc = 0.0f;
        for (int d = 0; d < D_; ++d) acc = fmaf(ff[d], wrow[d], acc);
        bhrs[idx] = acc;
    }
    __syncthreads();
    {
        int h = t >> 4, r = t & 15;
        dxs[t] = bhrs[h * 16 + r] - bhrs[(16 + h) * 16 + r];
    }
    __syncthreads();
    float acc = bout[t];
    const float* wrow = Wout + (size_t)t * 256;
    for (int c = 0; c < 256; ++c) acc = fmaf(dxs[c], wrow[c], acc);
    out[(size_t)b * D_ + t] = acc >= 0.0f ? acc : 0.01f * acc;
}

extern "C" void kernel_launch(void* const* d_in, const int* in_sizes, int n_in,
                              void* d_out, int out_size, void* d_ws, size_t ws_size,
                              hipStream_t stream) {
    const float* inp  = (const float*)d_in[0];
    // d_in[1] = batch_ids (equal-size contiguous graphs)
    const float* Wk   = (const float*)d_in[2];
    const float* Wq0  = (const float*)d_in[3];
    const float* Wq1  = (const float*)d_in[4];
    const float* We   = (const float*)d_in[5];
    const float* Wout = (const float*)d_in[6];
    const float* bout = (const float*)d_in[7];
    float* out = (float*)d_out;
    float* ws  = (float*)d_ws;
    float* pooledp = ws + POOLEDP_OFF;
    unsigned short* Phi = (unsigned short*)(ws + PHI_OFF);
    unsigned short* Plo = (unsigned short*)(ws + PLO_OFF);
    float* ml     = ws + ML_OFF;
    float* featp  = ws + FEATP_OFF;

    // opt-in for >64 KB dynamic LDS (no-op if already allowed); ignore errors
    static int lds_set = 0;
    if (!lds_set) {
        (void)hipFuncSetAttribute((const void*)k_attn,
                                  hipFuncAttributeMaxDynamicSharedMemorySize,
                                  LDS_BYTES);
        lds_set = 1;
    }

    k_pool<<<dim3(2048), dim3(256), 0, stream>>>(inp, pooledp);
    k_qp<<<dim3(128), dim3(256), 0, stream>>>(pooledp, Wq0, Wq1, Wk, Phi, Plo);
    k_attn<<<dim3(2048), dim3(512), LDS_BYTES, stream>>>(inp, Phi, Plo, ml, featp);
    k_out<<<dim3(128), dim3(256), 0, stream>>>(featp, ml, We, Wout, bout, out);
}

// Round 4
// 598.377 us; speedup vs baseline: 1.0252x; 1.0252x over previous
//
#include <hip/hip_runtime.h>
#include <math.h>

#define B_ 128
#define N_ 2048
#define D_ 256
#define NHEADS 32   // 2 head-sets * 16 heads
#define CHUNK 128   // nodes per LDS-resident chunk
#define CPB 4       // chunks per k_attn block (online-merged)
#define NBLK 4      // N_/(CHUNK*CPB) partials per graph

// ws layout (float offsets)
#define POOLEDP_OFF 0               // 16*B*256 = 524288 (per-chunk max partials)
#define PHI_OFF     524288          // B*32*256 ushort = 524288 fl
#define PLO_OFF     1048576         // 524288 fl
#define ML_OFF      1572864         // B*32*NBLK*2 = 32768
#define FEATP_OFF   1605632         // NBLK*B*256*32 = 4194304 (d-major)
                                    // end = 5799936 fl = 23 MB

// k_attn dynamic-LDS byte offsets (142208 B total, 1 block/CU)
#define XHI_S  0        // [128 n][256 d] bf16, row stride 512 B, 16B-slot XOR swizzle
#define XLO_S  65536    // same layout
#define ATT_S  131072   // [32 h][136 n] bf16, row stride 272 B = 8704 B
#define SMAX_S 139776   // [8 w][32 h] f32
#define SSUM_S 140800   // [8 w][32 h] f32
#define MRUN_S 141824   // [32] f32 running max
#define LRUN_S 141952   // [32] f32 running sum
#define RESC_S 142080   // [32] f32 rescale factor for current chunk
#define LDS_BYTES 142208

typedef __attribute__((ext_vector_type(8))) short short8;
typedef __attribute__((ext_vector_type(4))) float f32x4;

__device__ __forceinline__ unsigned short f2bf(float f) {   // RNE
    unsigned u = __float_as_uint(f);
    u += 0x7fff + ((u >> 16) & 1);
    return (unsigned short)(u >> 16);
}
__device__ __forceinline__ float bf2f(unsigned short h) {
    return __uint_as_float(((unsigned)h) << 16);
}
__device__ __forceinline__ unsigned pack2bf(float a, float b) {
    return (unsigned)f2bf(a) | ((unsigned)f2bf(b) << 16);
}
// 16B-slot swizzle within a 512 B row: spreads consecutive rows (phase-1 b128
// reads, 2-way) AND stride-8 rows (phase-3 u16 gathers, 4 distinct slots).
__device__ __forceinline__ unsigned xsw(int row) {
    return (unsigned)((row ^ (row >> 3)) & 7) << 4;
}

// pure max-pool, per-chunk partials (no atomics, no init kernel). grid B*16.
__global__ __launch_bounds__(256) void k_pool(const float* __restrict__ inp,
                                              float* __restrict__ pooledp) {
    int b = blockIdx.x >> 4;
    int ch = blockIdx.x & 15;
    int t = threadIdx.x;
    int sub = t >> 6;            // row phase 0..3
    int dq = (t & 63) * 4;       // column quad
    const float* p = inp + ((size_t)(b * N_ + ch * 128 + sub)) * D_ + dq;
    float4 m = {-INFINITY, -INFINITY, -INFINITY, -INFINITY};
#pragma unroll 4
    for (int i = 0; i < 32; ++i) {
        float4 v = *(const float4*)(p + (size_t)i * 4 * D_);
        m.x = fmaxf(m.x, v.x); m.y = fmaxf(m.y, v.y);
        m.z = fmaxf(m.z, v.z); m.w = fmaxf(m.w, v.w);
    }
    __shared__ float sm[4 * 256];
    sm[sub * 256 + dq + 0] = m.x;
    sm[sub * 256 + dq + 1] = m.y;
    sm[sub * 256 + dq + 2] = m.z;
    sm[sub * 256 + dq + 3] = m.w;
    __syncthreads();
    float v = fmaxf(fmaxf(sm[t], sm[256 + t]), fmaxf(sm[512 + t], sm[768 + t]));
    pooledp[((size_t)ch * B_ + b) * 256 + t] = v;
}

// merge pool partials, q = pooled @ Wq^T (both sets), P = q @ Wk -> bf16 hi/lo
__global__ __launch_bounds__(256) void k_qp(const float* __restrict__ pooledp,
                                            const float* __restrict__ Wq0,
                                            const float* __restrict__ Wq1,
                                            const float* __restrict__ Wk,
                                            unsigned short* __restrict__ Phi,
                                            unsigned short* __restrict__ Plo) {
    __shared__ float pl[D_];
    __shared__ float ql[1024];
    int b = blockIdx.x, t = threadIdx.x;
    float pv = -INFINITY;
#pragma unroll
    for (int i = 0; i < 16; ++i)
        pv = fmaxf(pv, pooledp[((size_t)i * B_ + b) * 256 + t]);
    pl[t] = pv;
    __syncthreads();
    for (int rep = 0; rep < 4; ++rep) {
        int idx = rep * 256 + t;                 // 0..1023
        const float* Wq = (idx < 512) ? Wq0 : Wq1;
        int row = idx & 511;
        const float4* wr = (const float4*)(Wq + (size_t)row * D_);
        float acc = 0.0f;
        for (int dqi = 0; dqi < 64; ++dqi) {
            float4 w = wr[dqi];
            const float* pp = &pl[dqi * 4];
            acc += w.x * pp[0] + w.y * pp[1] + w.z * pp[2] + w.w * pp[3];
        }
        ql[idx] = acc;
    }
    __syncthreads();
    float wk[32];
#pragma unroll
    for (int k = 0; k < 32; ++k) wk[k] = Wk[k * D_ + t];
    for (int j = 0; j < NHEADS; ++j) {
        const float* q = &ql[(j >> 4) * 512 + (j & 15) * 32];
        float acc = 0.0f;
#pragma unroll
        for (int k = 0; k < 32; ++k) acc = fmaf(q[k], wk[k], acc);
        unsigned short hi = f2bf(acc);
        unsigned short lo = f2bf(acc - bf2f(hi));
        Phi[((size_t)b * NHEADS + j) * D_ + t] = hi;
        Plo[((size_t)b * NHEADS + j) * D_ + t] = lo;
    }
}

// Fused attention, flash-style: each block owns 4 chunks of 128 nodes,
// online-merged (rescale O by exp(m_old - m_new) between chunks).
// Per chunk: stage inp fp32 -> LDS bf16 hi/lo (swizzled), S^T MFMA (hi/lo),
// chunk softmax w/ running max, O += att*x via in-LDS u16 transpose gather.
// grid = B*4 (b, blk); block 512 = 8 waves; dyn LDS 142 KB -> 1 block/CU.
// NOTE: ch-loop pinned to unroll 1 to cap codegen size / compile time.
__global__ __launch_bounds__(512, 2) void k_attn(const float* __restrict__ inp,
                                                 const unsigned short* __restrict__ Phi,
                                                 const unsigned short* __restrict__ Plo,
                                                 float* __restrict__ ml,
                                                 float* __restrict__ featp) {
    extern __shared__ unsigned char smem[];
    float* smax = (float*)(smem + SMAX_S);        // [8][32]
    float* ssum = (float*)(smem + SSUM_S);        // [8][32]
    float* mrun = (float*)(smem + MRUN_S);        // [32]
    float* lrun = (float*)(smem + LRUN_S);        // [32]
    float* resc = (float*)(smem + RESC_S);        // [32]

    int b = blockIdx.x >> 2, blk = blockIdx.x & 3;
    int t = threadIdx.x;
    int w = t >> 6;                // wave id 0..7
    int lane = t & 63;
    int lq = lane >> 4;            // quad 0..3
    int lm = lane & 15;

    if (t < 32) { mrun[t] = -INFINITY; lrun[t] = 0.0f; }

    f32x4 acc_o[2][2];
#pragma unroll
    for (int ht = 0; ht < 2; ++ht)
#pragma unroll
        for (int dt = 0; dt < 2; ++dt) acc_o[ht][dt] = (f32x4){0.f, 0.f, 0.f, 0.f};

    int arow = w * 16 + lm;                       // phase-1 A-frag row -> node
    unsigned abase = (unsigned)arow * 512u;
    unsigned asl = xsw(arow);
    int d0w = w * 32;                             // phase-3: wave owns 32 d-cols

#pragma unroll 1
    for (int ch = 0; ch < CPB; ++ch) {
        size_t gnode0 = (size_t)b * N_ + (size_t)(blk * CPB + ch) * CHUNK;

        // ------------- stage: inp fp32 -> LDS bf16 hi/lo -------------
        __syncthreads();   // previous chunk's phase-3 LDS readers done
#pragma unroll
        for (int i = 0; i < 16; ++i) {
            int row = i * 8 + w;
            float4 v = *(const float4*)(inp + (gnode0 + row) * D_ + lane * 4);
            ushort4 h4, l4;
            h4.x = f2bf(v.x); l4.x = f2bf(v.x - bf2f(h4.x));
            h4.y = f2bf(v.y); l4.y = f2bf(v.y - bf2f(h4.y));
            h4.z = f2bf(v.z); l4.z = f2bf(v.z - bf2f(h4.z));
            h4.w = f2bf(v.w); l4.w = f2bf(v.w - bf2f(h4.w));
            unsigned byteoff = (unsigned)row * 512u + (((unsigned)lane * 8u) ^ xsw(row));
            *(ushort4*)(smem + XHI_S + byteoff) = h4;
            *(ushort4*)(smem + XLO_S + byteoff) = l4;
        }
        __syncthreads();

        // ------------- phase 1: S^T accumulate -------------
        f32x4 acc_s[2];
        acc_s[0] = (f32x4){0.f, 0.f, 0.f, 0.f};
        acc_s[1] = (f32x4){0.f, 0.f, 0.f, 0.f};
#pragma unroll
        for (int dc = 0; dc < 8; ++dc) {
            short8 bh[2], bl[2];
#pragma unroll
            for (int ht = 0; ht < 2; ++ht) {
                size_t poff = ((size_t)b * NHEADS + ht * 16 + lm) * D_ + dc * 32 + lq * 8;
                bh[ht] = *(const short8*)(Phi + poff);
                bl[ht] = *(const short8*)(Plo + poff);
            }
            unsigned doff = (((unsigned)(dc * 32 + lq * 8)) * 2u) ^ asl;
            short8 ah = *(const short8*)(smem + XHI_S + abase + doff);
            short8 al = *(const short8*)(smem + XLO_S + abase + doff);
#pragma unroll
            for (int ht = 0; ht < 2; ++ht) {
                acc_s[ht] = __builtin_amdgcn_mfma_f32_16x16x32_bf16(ah, bh[ht], acc_s[ht], 0, 0, 0);
                acc_s[ht] = __builtin_amdgcn_mfma_f32_16x16x32_bf16(ah, bl[ht], acc_s[ht], 0, 0, 0);
                acc_s[ht] = __builtin_amdgcn_mfma_f32_16x16x32_bf16(al, bh[ht], acc_s[ht], 0, 0, 0);
            }
        }

        // ------------- phase 2: online chunk softmax -------------
        // lane holds S^T[n = w*16 + lq*4 + r][h = ht*16 + lm]
#pragma unroll
        for (int ht = 0; ht < 2; ++ht) {
            float m = fmaxf(fmaxf(acc_s[ht][0], acc_s[ht][1]),
                            fmaxf(acc_s[ht][2], acc_s[ht][3]));
            m = fmaxf(m, __shfl_xor(m, 16));
            m = fmaxf(m, __shfl_xor(m, 32));
            if (lane < 16) smax[w * 32 + ht * 16 + lane] = m;
        }
        __syncthreads();
        if (t < 32) {   // merge chunk max into running max, publish rescale
            float mc = smax[t];
#pragma unroll
            for (int w2 = 1; w2 < 8; ++w2) mc = fmaxf(mc, smax[w2 * 32 + t]);
            float mold = mrun[t];
            float mnew = fmaxf(mold, mc);
            resc[t] = __expf(mold - mnew);   // 0 on first chunk (mold=-inf)
            mrun[t] = mnew;
        }
        __syncthreads();
        // rescale O-accumulator (h = ht*16 + lq*4 + r)
#pragma unroll
        for (int ht = 0; ht < 2; ++ht) {
            f32x4 rs = *(const f32x4*)(resc + ht * 16 + lq * 4);
#pragma unroll
            for (int dt = 0; dt < 2; ++dt) {
#pragma unroll
                for (int r = 0; r < 4; ++r) acc_o[ht][dt][r] *= rs[r];
            }
        }
        float bm[2];
        bm[0] = mrun[lm];
        bm[1] = mrun[16 + lm];
#pragma unroll
        for (int ht = 0; ht < 2; ++ht) {
            float e0 = __expf(acc_s[ht][0] - bm[ht]);
            float e1 = __expf(acc_s[ht][1] - bm[ht]);
            float e2 = __expf(acc_s[ht][2] - bm[ht]);
            float e3 = __expf(acc_s[ht][3] - bm[ht]);
            float s = (e0 + e1) + (e2 + e3);
            uint2 pk;
            pk.x = pack2bf(e0, e1);
            pk.y = pack2bf(e2, e3);
            *(uint2*)(smem + ATT_S + (size_t)(ht * 16 + lm) * 272 + w * 32 + lq * 8) = pk;
            s += __shfl_xor(s, 16);
            s += __shfl_xor(s, 32);
            if (lane < 16) ssum[w * 32 + ht * 16 + lane] = s;
        }
        __syncthreads();
        if (t < 32) {   // merge chunk sum into running sum
            float l = ssum[t];
#pragma unroll
            for (int w2 = 1; w2 < 8; ++w2) l += ssum[w2 * 32 + t];
            lrun[t] = lrun[t] * resc[t] + l;
        }

        // ------------- phase 3: O += att * x (in-LDS transpose gather) -----
#pragma unroll
        for (int c = 0; c < 4; ++c) {  // K-chunks of 32 nodes
            short8 a0 = *(const short8*)(smem + ATT_S + (size_t)lm * 272 + c * 64 + lq * 16);
            short8 a1 = *(const short8*)(smem + ATT_S + (size_t)(16 + lm) * 272 + c * 64 + lq * 16);
#pragma unroll
            for (int dt = 0; dt < 2; ++dt) {
                unsigned d2 = (unsigned)(d0w + dt * 16 + lm) * 2u;
                int n0 = c * 32 + lq * 8;
                short8 bf;
#pragma unroll
                for (int j = 0; j < 8; ++j) {
                    int n = n0 + j;
                    unsigned byteoff = (unsigned)n * 512u + (d2 ^ xsw(n));
                    bf[j] = *(const short*)(smem + XHI_S + byteoff);
                }
                acc_o[0][dt] = __builtin_amdgcn_mfma_f32_16x16x32_bf16(a0, bf, acc_o[0][dt], 0, 0, 0);
                acc_o[1][dt] = __builtin_amdgcn_mfma_f32_16x16x32_bf16(a1, bf, acc_o[1][dt], 0, 0, 0);
            }
        }
    }

    // final (m, L) for this 512-node block
    if (t < 32) {
        float* mlp = ml + ((size_t)(b * NHEADS + t) * NBLK + blk) * 2;
        mlp[0] = mrun[t];
        mlp[1] = lrun[t];
    }
    // write featp (d-major: [blk][b][d][h]); C/D: col=lane&15 (d), row=lq*4+r (h)
    float* fb = featp + ((size_t)(blk * B_ + b)) * D_ * NHEADS;
#pragma unroll
    for (int ht = 0; ht < 2; ++ht)
#pragma unroll
        for (int dt = 0; dt < 2; ++dt) {
            int d = d0w + dt * 16 + lm;
            int h0 = ht * 16 + lq * 4;
            *(f32x4*)(fb + (size_t)d * NHEADS + h0) = acc_o[ht][dt];
        }
}

// epilogue: merge 4 block partials, feat@We^T, dx, dx@Wout^T + bias, leaky
__global__ __launch_bounds__(256) void k_out(const float* __restrict__ featp,
                                             const float* __restrict__ ml,
                                             const float* __restrict__ We,
                                             const float* __restrict__ Wout,
                                             const float* __restrict__ bout,
                                             float* __restrict__ out) {
    __shared__ float f[NHEADS * 257];
    __shared__ float bhrs[512];
    __shared__ float dxs[256];
    __shared__ float wns[NBLK * 32];
    __shared__ float linv2[32];
    int b = blockIdx.x, t = threadIdx.x;
    if (t < 32) {
        const float* mlb = ml + ((size_t)b * NHEADS + t) * (NBLK * 2);
        float M = fmaxf(fmaxf(mlb[0], mlb[2]), fmaxf(mlb[4], mlb[6]));
        float e0 = __expf(mlb[0] - M), e1 = __expf(mlb[2] - M);
        float e2 = __expf(mlb[4] - M), e3 = __expf(mlb[6] - M);
        float L = e0 * mlb[1] + e1 * mlb[3] + e2 * mlb[5] + e3 * mlb[7];
        wns[0 * 32 + t] = e0; wns[1 * 32 + t] = e1;
        wns[2 * 32 + t] = e2; wns[3 * 32 + t] = e3;
        linv2[t] = 1.0f / L;
    }
    __syncthreads();
    float fj[32];
#pragma unroll
    for (int j = 0; j < 32; ++j) fj[j] = 0.0f;
#pragma unroll 1
    for (int ns = 0; ns < NBLK; ++ns) {
        const float* fp = featp + ((size_t)(ns * B_ + b) * D_ + t) * NHEADS;
#pragma unroll
        for (int j4 = 0; j4 < 8; ++j4) {
            float4 v = *(const float4*)(fp + j4 * 4);
            fj[j4 * 4 + 0] += wns[ns * 32 + j4 * 4 + 0] * v.x;
            fj[j4 * 4 + 1] += wns[ns * 32 + j4 * 4 + 1] * v.y;
            fj[j4 * 4 + 2] += wns[ns * 32 + j4 * 4 + 2] * v.z;
            fj[j4 * 4 + 3] += wns[ns * 32 + j4 * 4 + 3] * v.w;
        }
    }
#pragma unroll
    for (int j = 0; j < 32; ++j) f[j * 257 + t] = fj[j] * linv2[j];
    __syncthreads();
    for (int rep = 0; rep < 2; ++rep) {
        int idx = rep * 256 + t;
        int j = idx >> 4, r = idx & 15;
        const float* wrow = We + (size_t)r * D_;
        const float* ff = &f[j * 257];
        float acc = 0.0f;
        for (int d = 0; d < D_; ++d) acc = fmaf(ff[d], wrow[d], acc);
        bhrs[idx] = acc;
    }
    __syncthreads();
    {
        int h = t >> 4, r = t & 15;
        dxs[t] = bhrs[h * 16 + r] - bhrs[(16 + h) * 16 + r];
    }
    __syncthreads();
    float acc = bout[t];
    const float* wrow = Wout + (size_t)t * 256;
    for (int c = 0; c < 256; ++c) acc = fmaf(dxs[c], wrow[c], acc);
    out[(size_t)b * D_ + t] = acc >= 0.0f ? acc : 0.01f * acc;
}

extern "C" void kernel_launch(void* const* d_in, const int* in_sizes, int n_in,
                              void* d_out, int out_size, void* d_ws, size_t ws_size,
                              hipStream_t stream) {
    const float* inp  = (const float*)d_in[0];
    // d_in[1] = batch_ids (equal-size contiguous graphs)
    const float* Wk   = (const float*)d_in[2];
    const float* Wq0  = (const float*)d_in[3];
    const float* Wq1  = (const float*)d_in[4];
    const float* We   = (const float*)d_in[5];
    const float* Wout = (const float*)d_in[6];
    const float* bout = (const float*)d_in[7];
    float* out = (float*)d_out;
    float* ws  = (float*)d_ws;
    float* pooledp = ws + POOLEDP_OFF;
    unsigned short* Phi = (unsigned short*)(ws + PHI_OFF);
    unsigned short* Plo = (unsigned short*)(ws + PLO_OFF);
    float* ml     = ws + ML_OFF;
    float* featp  = ws + FEATP_OFF;

    // opt-in for >64 KB dynamic LDS (host-side, capture-safe, once)
    static int lds_set = 0;
    if (!lds_set) {
        (void)hipFuncSetAttribute((const void*)k_attn,
                                  hipFuncAttributeMaxDynamicSharedMemorySize,
                                  LDS_BYTES);
        lds_set = 1;
    }

    k_pool<<<dim3(2048), dim3(256), 0, stream>>>(inp, pooledp);
    k_qp<<<dim3(128), dim3(256), 0, stream>>>(pooledp, Wq0, Wq1, Wk, Phi, Plo);
    k_attn<<<dim3(512), dim3(512), LDS_BYTES, stream>>>(inp, Phi, Plo, ml, featp);
    k_out<<<dim3(128), dim3(256), 0, stream>>>(featp, ml, We, Wout, bout, out);
}